// Round 15
// baseline (27890.204 us; speedup 1.0000x reference)
//
#include <hip/hip_runtime.h>
#include <hip/hip_bf16.h>

// Problem constants
#define HH 1024
#define BB 128
#define TT 512
#define NWG 128      // 4 row-groups (mg = wg>>5) x 32 N-slices (ng = wg&31)
#define NTH 512      // 8 waves: 4 output tiles (2M x 2N) x 2 K-halves (kh)
#define NP 32

typedef float        f32x4 __attribute__((ext_vector_type(4)));
typedef short        s16x8 __attribute__((ext_vector_type(8)));
typedef unsigned int u32x2 __attribute__((ext_vector_type(2)));

__device__ __forceinline__ unsigned short bf16b(float f) {
    union { __hip_bfloat16 h; unsigned short u; } cv;
    cv.h = __float2bfloat16(f);
    return cv.u;
}

__device__ __forceinline__ float gelu_exact(float x) {
    return 0.5f * x * (1.0f + erff(x * 0.70710678118654752440f));
}

// --- device-coherent (system-scope) accesses: cross-WG producer/consumer.
__device__ __forceinline__ void sc_load_b16x8(s16x8& v, const unsigned short* p) {
    asm volatile("global_load_dwordx4 %0, %1, off sc0 sc1" : "=v"(v) : "v"(p));
}
__device__ __forceinline__ void sc_load_u32x2(u32x2& v, const unsigned* p) {
    asm volatile("global_load_dwordx2 %0, %1, off sc0 sc1" : "=v"(v) : "v"(p));
}
__device__ __forceinline__ void sc_store_b16(unsigned short* p, unsigned int v) {
    asm volatile("global_store_short %0, %1, off sc0 sc1" :: "v"(p), "v"(v) : "memory");
}
__device__ __forceinline__ void sc_store_u32(unsigned* p, unsigned int v) {
    asm volatile("global_store_dword %0, %1, off sc0 sc1" :: "v"(p), "v"(v) : "memory");
}
// --- plain cached load (weights -> L2-resident under mod-8 mapping).
__device__ __forceinline__ void pl_load_b16x8(s16x8& v, const unsigned short* p) {
    asm volatile("global_load_dwordx4 %0, %1, off" : "=v"(v) : "v"(p));
}
// --- non-temporal store for streaming Out writes (no L2 pollution).
__device__ __forceinline__ void nt_store_f32(float* p, float v) {
    asm volatile("global_store_dword %0, %1, off nt" :: "v"(p), "v"(v) : "memory");
}

// ---------------------------------------------------------------------------
// Pack fp32 weight W[K][N] (row-major) into MFMA B-fragment layout, bf16.
// ---------------------------------------------------------------------------
__global__ __launch_bounds__(256) void pack_w_kernel(const float* __restrict__ W,
                                                     unsigned short* __restrict__ P,
                                                     int K, int N) {
    int tid = blockIdx.x * 256 + threadIdx.x;
    int KT = K >> 5;
    int total = (N >> 4) * KT * 64;
    if (tid >= total) return;
    int lane  = tid & 63;
    int ktile = (tid >> 6) % KT;
    int ntile = (tid >> 6) / KT;
    int k0 = ktile * 32 + (lane >> 4) * 8;
    int n  = ntile * 16 + (lane & 15);
    unsigned short tmp[8];
#pragma unroll
    for (int j = 0; j < 8; ++j)
        tmp[j] = bf16b(W[(size_t)(k0 + j) * N + n]);
    *reinterpret_cast<s16x8*>(P + (size_t)tid * 8) = *reinterpret_cast<const s16x8*>(tmp);
}

// ---------------------------------------------------------------------------
// Pack fp32 X into bf16 (identical rounding to the on-the-fly path).
// ---------------------------------------------------------------------------
__global__ __launch_bounds__(256) void pack_x_kernel(const float* __restrict__ X,
                                                     unsigned short* __restrict__ Xb,
                                                     int n8) {
    int i = blockIdx.x * 256 + threadIdx.x;
    if (i >= n8) return;
    f32x4 lo = *reinterpret_cast<const f32x4*>(X + (size_t)i * 8);
    f32x4 hi = *reinterpret_cast<const f32x4*>(X + (size_t)i * 8 + 4);
    unsigned short tmp[8];
#pragma unroll
    for (int j = 0; j < 4; ++j) {
        tmp[j]     = bf16b(lo[j]);
        tmp[j + 4] = bf16b(hi[j]);
    }
    *reinterpret_cast<s16x8*>(Xb + (size_t)i * 8) = *reinterpret_cast<const s16x8*>(tmp);
}

// ---------------------------------------------------------------------------
// r4/r13's PROVEN GLOBAL flag-array barrier (verbatim — no group drift).
// ---------------------------------------------------------------------------
__device__ __forceinline__ void gbar_arrive(unsigned* slots, unsigned rnd) {
    asm volatile("s_waitcnt vmcnt(0)" ::: "memory");  // drain my sc/nt stores
    __syncthreads();                                   // all 8 waves drained
    if (threadIdx.x == 0)
        sc_store_u32(slots + blockIdx.x, rnd);
}
__device__ __forceinline__ void gbar_wait(unsigned* slots, unsigned rnd) {
    if (threadIdx.x < 64) {
        const unsigned* p = slots + (threadIdx.x << 1);
        bool done;
        do {
            u32x2 v;
            sc_load_u32x2(v, p);
            asm volatile("s_waitcnt vmcnt(0)" ::: "memory");
            done = __all(v.x >= rnd && v.y >= rnd);
        } while (!done);
    }
    __syncthreads();
    __builtin_amdgcn_sched_barrier(0);
}

// ---------------------------------------------------------------------------
// 16-kt K-loop, UPFRONT ISSUE: all 16 A (sc) + 16 B (plain) issued in one
// interleaved burst (32 outstanding <= 63 cap) -> ONE round-trip of exposed
// latency; counted vmcnt(16)/vmcnt(0) splits the MFMA into 2 batches.
// ---------------------------------------------------------------------------
__device__ __forceinline__ f32x4 kloop_g16(const unsigned short* Abase,
                                           const unsigned short* bp,
                                           f32x4 acc) {
    s16x8 a[16], b[16];
#pragma unroll
    for (int j = 0; j < 8; ++j) sc_load_b16x8(a[j], Abase + (size_t)j * 32);
#pragma unroll
    for (int j = 0; j < 8; ++j) pl_load_b16x8(b[j], bp + (size_t)j * 512);
#pragma unroll
    for (int j = 8; j < 16; ++j) sc_load_b16x8(a[j], Abase + (size_t)j * 32);
#pragma unroll
    for (int j = 8; j < 16; ++j) pl_load_b16x8(b[j], bp + (size_t)j * 512);
    asm volatile("s_waitcnt vmcnt(16)" ::: "memory");
    __builtin_amdgcn_sched_barrier(0);
#pragma unroll
    for (int j = 0; j < 8; ++j)
        acc = __builtin_amdgcn_mfma_f32_16x16x32_bf16(a[j], b[j], acc, 0, 0, 0);
    asm volatile("s_waitcnt vmcnt(0)" ::: "memory");
    __builtin_amdgcn_sched_barrier(0);
#pragma unroll
    for (int j = 8; j < 16; ++j)
        acc = __builtin_amdgcn_mfma_f32_16x16x32_bf16(a[j], b[j], acc, 0, 0, 0);
    return acc;
}

// ---------------------------------------------------------------------------
// 16-kt K-loop, A upfront (16 sc loads, one RT), B from LDS-pinned weights.
// ---------------------------------------------------------------------------
__device__ __forceinline__ f32x4 kloop_ds16(const unsigned short* Abase,
                                            const char* wl) {
    f32x4 acc = {};
    s16x8 a[16];
#pragma unroll
    for (int j = 0; j < 16; ++j) sc_load_b16x8(a[j], Abase + (size_t)j * 32);
    asm volatile("s_waitcnt vmcnt(8)" ::: "memory");
    __builtin_amdgcn_sched_barrier(0);
#pragma unroll
    for (int j = 0; j < 8; ++j) {
        s16x8 b = *reinterpret_cast<const s16x8*>(wl + (size_t)j * 1024);
        acc = __builtin_amdgcn_mfma_f32_16x16x32_bf16(a[j], b, acc, 0, 0, 0);
    }
    asm volatile("s_waitcnt vmcnt(0)" ::: "memory");
    __builtin_amdgcn_sched_barrier(0);
#pragma unroll
    for (int j = 8; j < 16; ++j) {
        s16x8 b = *reinterpret_cast<const s16x8*>(wl + (size_t)j * 1024);
        acc = __builtin_amdgcn_mfma_f32_16x16x32_bf16(a[j], b, acc, 0, 0, 0);
    }
    return acc;
}

// 16-kt x-half loop (bf16 pre-packed X, plain cached loads, compiler-
// scheduled). Runs BEFORE the barrier wait (static input).
__device__ __forceinline__ f32x4 kloop_xb16(const unsigned short* xtb,
                                            const unsigned short* bp) {
    f32x4 acc = {};
#pragma unroll 8
    for (int kt = 0; kt < 16; ++kt) {
        s16x8 a = *reinterpret_cast<const s16x8*>(xtb + kt * 32);
        s16x8 b = *reinterpret_cast<const s16x8*>(bp + (size_t)kt * 512);
        acc = __builtin_amdgcn_mfma_f32_16x16x32_bf16(a, b, acc, 0, 0, 0);
    }
    return acc;
}

// ---------------------------------------------------------------------------
// Persistent kernel = r13 structure + kh-split 1-RT kloops (ONLY delta).
// Mapping (r13-proven): ng = wg&31 (mod-8 XCD-friendly -> G1/G3 weights
// 1 MB/XCD, L2-resident), mg = wg>>5. GLOBAL barrier (lock-step, no drift).
// 8 waves: tile = w&3 (2M x 2N of 16x16), kh = w>>2 splits EVERY K-loop;
// kh-1 partials reduced into kh-0 via 4 KB LDS.
// G2/G4 weights (128 KB) pinned in LDS. X bf16-prepacked, x-half hoisted
// before the wait. Activations sc0sc1; Out nt.
// ---------------------------------------------------------------------------
__global__ __launch_bounds__(512, 1) void persist_kernel(
    const float* __restrict__ X, const unsigned short* __restrict__ Xb,
    const unsigned short* __restrict__ p_a1, const float* __restrict__ ab1,
    const unsigned short* __restrict__ p_a2, const float* __restrict__ ab2,
    const unsigned short* __restrict__ p_g1, const float* __restrict__ gb1,
    const unsigned short* __restrict__ p_g2, const float* __restrict__ gb2,
    float* __restrict__ Out,
    unsigned short* state, unsigned short* h1, unsigned short* albf,
    unsigned short* h2,
    unsigned* slots)
{
    __shared__ __align__(16) char wlds[131072];   // 128 KB G2/G4 weight frags
    __shared__ f32x4 red[4][64];                  // 4 KB split-K reduction

    const int wg    = blockIdx.x;
    const int ng    = wg & (NP - 1);  // mod-8 XCD-friendly N-slice
    const int mg    = wg >> 5;        // row-group
    const int tid   = threadIdx.x;
    const int lane  = tid & 63;
    const int w     = tid >> 6;       // 0..7
    const int tile  = w & 3;          // 2M x 2N
    const int kh    = w >> 2;         // 0..1 K-half
    const int wm    = tile >> 1;
    const int wn    = tile & 1;
    const int r     = lane & 15;
    const int q     = lane >> 4;

    const int mrow  = mg * 32 + wm * 16;
    const int ncol  = ng * 32 + wn * 16;
    const int ntile = ncol >> 4;          // = ng*2 + wn

    const size_t arow_off = (size_t)(mrow + r) * HH + q * 8;
    const unsigned short* xrowb = Xb + (size_t)(mrow + r) * (TT * HH) + q * 8;

    const unsigned short* bpa1 = p_a1 + ((size_t)ntile * 64) * 512 + (size_t)lane * 8;
    const unsigned short* bpg1 = p_g1 + ((size_t)ntile * 64) * 512 + (size_t)lane * 8;

    const float biasA1 = ab1[ncol + r];
    const float biasA2 = ab2[ncol + r];
    const float biasG1 = gb1[ncol + r];
    const float biasG2 = gb2[ncol + r];

    // ---- prologue: pin this WG's G2/G4 weight fragments in LDS -----------
    for (int idx = tid; idx < 8192; idx += NTH) {
        int g   = idx >> 12;
        int rem = idx & 4095;
        int ntl = rem >> 11;
        int kt  = (rem >> 6) & 31;
        int ln  = rem & 63;
        const unsigned short* src = (g ? p_g2 : p_a2)
            + ((size_t)((ng * 2 + ntl) * 32 + kt) * 64 + ln) * 8;
        *reinterpret_cast<s16x8*>(wlds + (size_t)idx * 16) =
            *reinterpret_cast<const s16x8*>(src);
    }
    __syncthreads();

    const char* wl_a2 = wlds + (size_t)wn * 32768 + (size_t)kh * 16384
                             + (size_t)lane * 16;
    const char* wl_g2 = wl_a2 + 65536;

    // kh-dependent K-segment offsets (16 kt = 512 A elements, 16*512 B frags)
    const size_t aseg = (size_t)kh * 512;
    const size_t bseg = (size_t)kh * 16 * 512;

    float al_reg[4] = {0.f, 0.f, 0.f, 0.f};   // fp32 'aligned' tile (kh 0)

    for (int t = 0; t < TT; ++t) {
        const unsigned short* xtb = xrowb + (size_t)t * HH;
        const unsigned rb = 4u * (unsigned)t;

        // ------- G1: h1 = gelu(concat(x_t, state) @ aw1 + ab1), K=2048 -----
        {
            // x half (this wave's 16 kt) BEFORE the wait — static input
            f32x4 acc = kloop_xb16(xtb + aseg, bpa1 + bseg);
            gbar_wait(slots, rb);                        // state ready (G4 t-1)
            // state half (this wave's 16 kt), one-RT upfront-issue
            acc = kloop_g16(state + arow_off + aseg,
                            bpa1 + (size_t)32 * 512 + bseg, acc);
            if (kh == 1) red[tile][lane] = acc;
            __syncthreads();
            if (kh == 0) {
                acc += red[tile][lane];
#pragma unroll
                for (int j = 0; j < 4; ++j) {
                    float v = acc[j] + biasA1;
                    sc_store_b16(h1 + (size_t)(mrow + q * 4 + j) * HH + ncol + r,
                                 bf16b(gelu_exact(v)));
                }
            }
        }
        gbar_arrive(slots, rb + 1);

        // ------- G2: aligned = h1 @ aw2 + ab2, K=1024 (B from LDS) ---------
        {
            gbar_wait(slots, rb + 1);
            f32x4 acc = kloop_ds16(h1 + arow_off + aseg, wl_a2);
            if (kh == 1) red[tile][lane] = acc;
            __syncthreads();
            if (kh == 0) {
                acc += red[tile][lane];
#pragma unroll
                for (int j = 0; j < 4; ++j) {
                    float v = acc[j] + biasA2;
                    al_reg[j] = v;
                    sc_store_b16(albf + (size_t)(mrow + q * 4 + j) * HH + ncol + r,
                                 bf16b(v));
                }
            }
        }
        gbar_arrive(slots, rb + 2);

        // ------- G3: h2 = gelu(concat(x_t, aligned) @ gw1 + gb1), K=2048 ---
        {
            f32x4 acc = kloop_xb16(xtb + aseg, bpg1 + bseg);   // x half first
            gbar_wait(slots, rb + 2);                          // albf ready
            acc = kloop_g16(albf + arow_off + aseg,
                            bpg1 + (size_t)32 * 512 + bseg, acc);
            if (kh == 1) red[tile][lane] = acc;
            __syncthreads();
            if (kh == 0) {
                acc += red[tile][lane];
#pragma unroll
                for (int j = 0; j < 4; ++j) {
                    float v = acc[j] + biasG1;
                    sc_store_b16(h2 + (size_t)(mrow + q * 4 + j) * HH + ncol + r,
                                 bf16b(gelu_exact(v)));
                }
            }
        }
        gbar_arrive(slots, rb + 3);

        // ------- G4: gate = sigmoid(h2 @ gw2 + gb2); blend (B from LDS) ----
        {
            gbar_wait(slots, rb + 3);
            f32x4 acc = kloop_ds16(h2 + arow_off + aseg, wl_g2);
            if (kh == 1) red[tile][lane] = acc;
            __syncthreads();
            if (kh == 0) {
                acc += red[tile][lane];
#pragma unroll
                for (int j = 0; j < 4; ++j) {
                    int row = mrow + q * 4 + j;
                    int col = ncol + r;
                    float gl = acc[j] + biasG2;
                    float g  = 1.0f / (1.0f + expf(-gl));
                    float xv = X[(size_t)row * (TT * HH) + (size_t)t * HH + col];
                    float o  = g * al_reg[j] + (1.0f - g) * xv;
                    nt_store_f32(Out + (size_t)row * (TT * HH) + (size_t)t * HH + col, o);
                    sc_store_b16(state + (size_t)row * HH + col, bf16b(o));
                }
            }
        }
        gbar_arrive(slots, rb + 4);
    }
}

extern "C" void kernel_launch(void* const* d_in, const int* in_sizes, int n_in,
                              void* d_out, int out_size, void* d_ws, size_t ws_size,
                              hipStream_t stream) {
    (void)in_sizes; (void)n_in; (void)out_size; (void)ws_size;
    const float* X   = (const float*)d_in[0];
    const float* aw1 = (const float*)d_in[1];
    const float* ab1 = (const float*)d_in[2];
    const float* aw2 = (const float*)d_in[3];
    const float* ab2 = (const float*)d_in[4];
    const float* gw1 = (const float*)d_in[5];
    const float* gb1 = (const float*)d_in[6];
    const float* gw2 = (const float*)d_in[7];
    const float* gb2 = (const float*)d_in[8];
    float* Out = (float*)d_out;

    char* ws = (char*)d_ws;
    unsigned short* p_a1 = (unsigned short*)(ws);                 // 4 MB
    unsigned short* p_g1 = (unsigned short*)(ws + (4u  << 20));   // 4 MB
    unsigned short* p_a2 = (unsigned short*)(ws + (8u  << 20));   // 2 MB
    unsigned short* p_g2 = (unsigned short*)(ws + (10u << 20));   // 2 MB
    char* ctrl = ws + (12u << 20);
    unsigned* slots = (unsigned*)ctrl;                            // 128 u32 (dense, r4)
    unsigned short* state = (unsigned short*)(ctrl + 4096);       // 256 KB
    unsigned short* h1    = state + (size_t)BB * HH;              // 256 KB
    unsigned short* albf  = h1    + (size_t)BB * HH;              // 256 KB
    unsigned short* h2    = albf  + (size_t)BB * HH;              // 256 KB
    unsigned short* xbf   = (unsigned short*)(ws + (16u << 20));  // 128 MB

    pack_w_kernel<<<(64 * 64 * 64 + 255) / 256, 256, 0, stream>>>(aw1, p_a1, 2048, 1024);
    pack_w_kernel<<<(64 * 64 * 64 + 255) / 256, 256, 0, stream>>>(gw1, p_g1, 2048, 1024);
    pack_w_kernel<<<(64 * 32 * 64 + 255) / 256, 256, 0, stream>>>(aw2, p_a2, 1024, 1024);
    pack_w_kernel<<<(64 * 32 * 64 + 255) / 256, 256, 0, stream>>>(gw2, p_g2, 1024, 1024);
    {
        int n8 = BB * TT * HH / 8;
        pack_x_kernel<<<(n8 + 255) / 256, 256, 0, stream>>>(X, xbf, n8);
    }
    // Zero barrier slots + recurrent state every call (graph-replay safe).
    hipMemsetAsync(ctrl, 0, 4096 + (size_t)BB * HH * sizeof(unsigned short), stream);

    persist_kernel<<<NWG, NTH, 0, stream>>>(X, xbf, p_a1, ab1, p_a2, ab2,
                                            p_g1, gb1, p_g2, gb2,
                                            Out, state, h1, albf, h2, slots);
}

// Round 16
// 19567.587 us; speedup vs baseline: 1.4253x; 1.4253x over previous
//
#include <hip/hip_runtime.h>
#include <hip/hip_bf16.h>

// Problem constants
#define HH 1024
#define BB 128
#define TT 512
#define NWG 128      // 4 row-groups (mg = wg>>5) x 32 N-slices (ng = wg&31)
#define NTH 512      // 8 waves: 4 output tiles (2M x 2N) x 2 K-halves
#define NP 32

typedef float        f32x4 __attribute__((ext_vector_type(4)));
typedef short        s16x8 __attribute__((ext_vector_type(8)));

__device__ __forceinline__ unsigned short bf16b(float f) {
    union { __hip_bfloat16 h; unsigned short u; } cv;
    cv.h = __float2bfloat16(f);
    return cv.u;
}

__device__ __forceinline__ float gelu_exact(float x) {
    return 0.5f * x * (1.0f + erff(x * 0.70710678118654752440f));
}

// --- device-coherent (system-scope) accesses: cross-WG producer/consumer.
__device__ __forceinline__ void sc_load_b16x8(s16x8& v, const unsigned short* p) {
    asm volatile("global_load_dwordx4 %0, %1, off sc0 sc1" : "=v"(v) : "v"(p));
}
__device__ __forceinline__ void sc_load_u32(unsigned& v, const unsigned* p) {
    asm volatile("global_load_dword %0, %1, off sc0 sc1" : "=v"(v) : "v"(p));
}
__device__ __forceinline__ void sc_store_b16(unsigned short* p, unsigned int v) {
    asm volatile("global_store_short %0, %1, off sc0 sc1" :: "v"(p), "v"(v) : "memory");
}
__device__ __forceinline__ void sc_store_u32(unsigned* p, unsigned int v) {
    asm volatile("global_store_dword %0, %1, off sc0 sc1" :: "v"(p), "v"(v) : "memory");
}
// --- plain cached load (weights -> L2-resident under mod-8 mapping).
__device__ __forceinline__ void pl_load_b16x8(s16x8& v, const unsigned short* p) {
    asm volatile("global_load_dwordx4 %0, %1, off" : "=v"(v) : "v"(p));
}
// --- non-temporal store for streaming Out writes (no L2 pollution).
__device__ __forceinline__ void nt_store_f32(float* p, float v) {
    asm volatile("global_store_dword %0, %1, off nt" :: "v"(p), "v"(v) : "memory");
}
__device__ __forceinline__ void vm_wait0() {
    asm volatile("s_waitcnt vmcnt(0)" ::: "memory");
    __builtin_amdgcn_sched_barrier(0);   // rule #18
}

// ---------------------------------------------------------------------------
// Pack fp32 weight W[K][N] (row-major) into MFMA B-fragment layout, bf16.
// ---------------------------------------------------------------------------
__global__ __launch_bounds__(256) void pack_w_kernel(const float* __restrict__ W,
                                                     unsigned short* __restrict__ P,
                                                     int K, int N) {
    int tid = blockIdx.x * 256 + threadIdx.x;
    int KT = K >> 5;
    int total = (N >> 4) * KT * 64;
    if (tid >= total) return;
    int lane  = tid & 63;
    int ktile = (tid >> 6) % KT;
    int ntile = (tid >> 6) / KT;
    int k0 = ktile * 32 + (lane >> 4) * 8;
    int n  = ntile * 16 + (lane & 15);
    unsigned short tmp[8];
#pragma unroll
    for (int j = 0; j < 8; ++j)
        tmp[j] = bf16b(W[(size_t)(k0 + j) * N + n]);
    *reinterpret_cast<s16x8*>(P + (size_t)tid * 8) = *reinterpret_cast<const s16x8*>(tmp);
}

// ---------------------------------------------------------------------------
// Pack fp32 X into bf16 (identical rounding to the on-the-fly path).
// ---------------------------------------------------------------------------
__global__ __launch_bounds__(256) void pack_x_kernel(const float* __restrict__ X,
                                                     unsigned short* __restrict__ Xb,
                                                     int n8) {
    int i = blockIdx.x * 256 + threadIdx.x;
    if (i >= n8) return;
    f32x4 lo = *reinterpret_cast<const f32x4*>(X + (size_t)i * 8);
    f32x4 hi = *reinterpret_cast<const f32x4*>(X + (size_t)i * 8 + 4);
    unsigned short tmp[8];
#pragma unroll
    for (int j = 0; j < 4; ++j) {
        tmp[j]     = bf16b(lo[j]);
        tmp[j + 4] = bf16b(hi[j]);
    }
    *reinterpret_cast<s16x8*>(Xb + (size_t)i * 8) = *reinterpret_cast<const s16x8*>(tmp);
}

// ---------------------------------------------------------------------------
// Per-GROUP flag barrier (32 WGs of one row-group; all deps are mg-local).
// Slots dense: 32 u32 = 128 B (2 lines) per group; groups 256 B apart.
// Arrive: drain stores, block sync, one sc-store (r4 shape). Wait: wave 0
// polls the 32 slots (lane&31 -> 1 dword), then block sync. Same mechanism
// as the proven r4/r13 global barrier, scoped 4x smaller.
// ---------------------------------------------------------------------------
__device__ __forceinline__ void gbar_arrive(unsigned* gs, int ng, unsigned rnd) {
    asm volatile("s_waitcnt vmcnt(0)" ::: "memory");  // drain my sc/nt stores
    __syncthreads();                                   // all 8 waves drained
    if (threadIdx.x == 0)
        sc_store_u32(gs + ng, rnd);
}
__device__ __forceinline__ void gbar_wait(unsigned* gs, unsigned rnd) {
    if (threadIdx.x < 64) {
        const unsigned* p = gs + (threadIdx.x & 31);
        bool done;
        do {
            unsigned v;
            sc_load_u32(v, p);
            asm volatile("s_waitcnt vmcnt(0)" ::: "memory");
            done = __all(v >= rnd);
        } while (!done);
    }
    __syncthreads();
    __builtin_amdgcn_sched_barrier(0);
}

// ---------------------------------------------------------------------------
// r4/r13's trickle K-loop (verbatim — the FETCH-safe shape): A via sc loads,
// B via plain cached loads, 8 kt per batch, vmcnt(0) per batch.
// ---------------------------------------------------------------------------
template <int NBLK>
__device__ __forceinline__ f32x4 kloop_sc(const unsigned short* Abase,
                                          const unsigned short* bp) {
    f32x4 acc = {};
    for (int blk = 0; blk < NBLK; ++blk) {
        int kb = blk * 8;
        s16x8 a[8], b[8];
#pragma unroll
        for (int j = 0; j < 8; ++j)
            sc_load_b16x8(a[j], Abase + (size_t)(kb + j) * 32);
#pragma unroll
        for (int j = 0; j < 8; ++j)
            b[j] = *reinterpret_cast<const s16x8*>(bp + (size_t)(kb + j) * 512);
        vm_wait0();
#pragma unroll
        for (int j = 0; j < 8; ++j)
            acc = __builtin_amdgcn_mfma_f32_16x16x32_bf16(a[j], b[j], acc, 0, 0, 0);
    }
    return acc;
}

// ---------------------------------------------------------------------------
// G2/G4 K-half loop (r11/r13-proven): A via sc loads (2-deep counted vmcnt),
// B from LDS-pinned weights.
// ---------------------------------------------------------------------------
__device__ __forceinline__ f32x4 kloop_ds(const unsigned short* Abase,
                                          const char* wl) {
    f32x4 acc = {};
    s16x8 a[2][8];
#pragma unroll
    for (int j = 0; j < 8; ++j)
        sc_load_b16x8(a[0][j], Abase + (size_t)j * 32);
#pragma unroll
    for (int blk = 0; blk < 2; ++blk) {
        const int cur = blk & 1, nxt = cur ^ 1;
        if (blk == 0) {
#pragma unroll
            for (int j = 0; j < 8; ++j)
                sc_load_b16x8(a[nxt][j], Abase + (size_t)(8 + j) * 32);
            asm volatile("s_waitcnt vmcnt(8)" ::: "memory");
        } else {
            asm volatile("s_waitcnt vmcnt(0)" ::: "memory");
        }
        __builtin_amdgcn_sched_barrier(0);
#pragma unroll
        for (int j = 0; j < 8; ++j) {
            s16x8 b = *reinterpret_cast<const s16x8*>(wl + (size_t)(blk * 8 + j) * 1024);
            acc = __builtin_amdgcn_mfma_f32_16x16x32_bf16(a[cur][j], b, acc, 0, 0, 0);
        }
    }
    return acc;
}

// x-half K-loop (bf16 pre-packed X, plain cached loads, compiler-scheduled).
// Runs BEFORE the barrier wait (static input).
__device__ __forceinline__ f32x4 kloop_xb(const unsigned short* xtb,
                                          const unsigned short* bp) {
    f32x4 acc = {};
#pragma unroll 8
    for (int kt = 0; kt < 32; ++kt) {
        s16x8 a = *reinterpret_cast<const s16x8*>(xtb + kt * 32);
        s16x8 b = *reinterpret_cast<const s16x8*>(bp + (size_t)kt * 512);
        acc = __builtin_amdgcn_mfma_f32_16x16x32_bf16(a, b, acc, 0, 0, 0);
    }
    return acc;
}

// ---------------------------------------------------------------------------
// Persistent kernel = r13 verbatim, ONLY the barrier scoped per-group.
// Mapping (r13-proven): ng = wg&31 (mod-8 XCD-friendly -> G1/G3 weights
// 1 MB/XCD, L2-resident), mg = wg>>5. Weights are t-invariant, so group
// drift cannot evict them. 8 waves: tile = w&3 (2M x 2N of 16x16),
// khalf = w>>2 splits K; khalf-1 partials reduced into khalf-0 via LDS.
// G2/G4 weights (128 KB) pinned in LDS. X bf16-prepacked, x-half hoisted.
// Activations sc0sc1; Out nt.
// ---------------------------------------------------------------------------
__global__ __launch_bounds__(512, 1) void persist_kernel(
    const float* __restrict__ X, const unsigned short* __restrict__ Xb,
    const unsigned short* __restrict__ p_a1, const float* __restrict__ ab1,
    const unsigned short* __restrict__ p_a2, const float* __restrict__ ab2,
    const unsigned short* __restrict__ p_g1, const float* __restrict__ gb1,
    const unsigned short* __restrict__ p_g2, const float* __restrict__ gb2,
    float* __restrict__ Out,
    unsigned short* state, unsigned short* h1, unsigned short* albf,
    unsigned short* h2,
    unsigned* slots)
{
    __shared__ __align__(16) char wlds[131072];   // 128 KB G2/G4 weight frags
    __shared__ f32x4 red[4][64];                  // 4 KB split-K reduction

    const int wg    = blockIdx.x;
    const int ng    = wg & (NP - 1);  // mod-8 XCD-friendly N-slice
    const int mg    = wg >> 5;        // row-group
    const int tid   = threadIdx.x;
    const int lane  = tid & 63;
    const int w     = tid >> 6;       // 0..7
    const int tile  = w & 3;          // 2M x 2N
    const int khalf = w >> 2;         // 0..1
    const int wm    = tile >> 1;
    const int wn    = tile & 1;
    const int r     = lane & 15;
    const int q     = lane >> 4;

    const int mrow  = mg * 32 + wm * 16;
    const int ncol  = ng * 32 + wn * 16;
    const int ntile = ncol >> 4;          // = ng*2 + wn

    unsigned* gs = slots + mg * 64;       // group's dense 32-slot block (256B apart)

    const size_t arow_off = (size_t)(mrow + r) * HH + q * 8;
    const unsigned short* xrowb = Xb + (size_t)(mrow + r) * (TT * HH) + q * 8;

    const unsigned short* bpa1 = p_a1 + ((size_t)ntile * 64) * 512 + (size_t)lane * 8;
    const unsigned short* bpg1 = p_g1 + ((size_t)ntile * 64) * 512 + (size_t)lane * 8;

    const float biasA1 = ab1[ncol + r];
    const float biasA2 = ab2[ncol + r];
    const float biasG1 = gb1[ncol + r];
    const float biasG2 = gb2[ncol + r];

    // ---- prologue: pin this WG's G2/G4 weight fragments in LDS -----------
    for (int idx = tid; idx < 8192; idx += NTH) {
        int g   = idx >> 12;
        int rem = idx & 4095;
        int ntl = rem >> 11;
        int kt  = (rem >> 6) & 31;
        int ln  = rem & 63;
        const unsigned short* src = (g ? p_g2 : p_a2)
            + ((size_t)((ng * 2 + ntl) * 32 + kt) * 64 + ln) * 8;
        *reinterpret_cast<s16x8*>(wlds + (size_t)idx * 16) =
            *reinterpret_cast<const s16x8*>(src);
    }
    __syncthreads();

    const char* wl_a2 = wlds + (size_t)wn * 32768 + (size_t)khalf * 16384
                             + (size_t)lane * 16;
    const char* wl_g2 = wl_a2 + 65536;

    float al_reg[4] = {0.f, 0.f, 0.f, 0.f};   // fp32 'aligned' tile (khalf 0)

    for (int t = 0; t < TT; ++t) {
        const unsigned short* xtb = xrowb + (size_t)t * HH;
        const unsigned rb = 4u * (unsigned)t;

        // ------- G1: h1 = gelu(concat(x_t, state) @ aw1 + ab1), K=2048 -----
        {
            f32x4 acc;
            if (khalf == 0) acc = kloop_xb(xtb, bpa1);   // x half BEFORE wait
            gbar_wait(gs, rb);                           // state ready (G4 t-1)
            if (khalf == 1) {
                acc = kloop_sc<4>(state + arow_off, bpa1 + (size_t)32 * 512);
                red[tile][lane] = acc;
            }
            __syncthreads();
            if (khalf == 0) {
                acc += red[tile][lane];
#pragma unroll
                for (int j = 0; j < 4; ++j) {
                    float v = acc[j] + biasA1;
                    sc_store_b16(h1 + (size_t)(mrow + q * 4 + j) * HH + ncol + r,
                                 bf16b(gelu_exact(v)));
                }
            }
        }
        gbar_arrive(gs, ng, rb + 1);

        // ------- G2: aligned = h1 @ aw2 + ab2, K=1024 (B from LDS) ---------
        {
            gbar_wait(gs, rb + 1);
            f32x4 acc = kloop_ds(h1 + arow_off + (size_t)khalf * 512, wl_a2);
            if (khalf == 1) red[tile][lane] = acc;
            __syncthreads();
            if (khalf == 0) {
                acc += red[tile][lane];
#pragma unroll
                for (int j = 0; j < 4; ++j) {
                    float v = acc[j] + biasA2;
                    al_reg[j] = v;
                    sc_store_b16(albf + (size_t)(mrow + q * 4 + j) * HH + ncol + r,
                                 bf16b(v));
                }
            }
        }
        gbar_arrive(gs, ng, rb + 2);

        // ------- G3: h2 = gelu(concat(x_t, aligned) @ gw1 + gb1), K=2048 ---
        {
            f32x4 acc;
            if (khalf == 0) acc = kloop_xb(xtb, bpg1);   // x half BEFORE wait
            gbar_wait(gs, rb + 2);                       // albf ready
            if (khalf == 1) {
                acc = kloop_sc<4>(albf + arow_off, bpg1 + (size_t)32 * 512);
                red[tile][lane] = acc;
            }
            __syncthreads();
            if (khalf == 0) {
                acc += red[tile][lane];
#pragma unroll
                for (int j = 0; j < 4; ++j) {
                    float v = acc[j] + biasG1;
                    sc_store_b16(h2 + (size_t)(mrow + q * 4 + j) * HH + ncol + r,
                                 bf16b(gelu_exact(v)));
                }
            }
        }
        gbar_arrive(gs, ng, rb + 3);

        // ------- G4: gate = sigmoid(h2 @ gw2 + gb2); blend (B from LDS) ----
        {
            gbar_wait(gs, rb + 3);
            f32x4 acc = kloop_ds(h2 + arow_off + (size_t)khalf * 512, wl_g2);
            if (khalf == 1) red[tile][lane] = acc;
            __syncthreads();
            if (khalf == 0) {
                acc += red[tile][lane];
#pragma unroll
                for (int j = 0; j < 4; ++j) {
                    int row = mrow + q * 4 + j;
                    int col = ncol + r;
                    float gl = acc[j] + biasG2;
                    float g  = 1.0f / (1.0f + expf(-gl));
                    float xv = X[(size_t)row * (TT * HH) + (size_t)t * HH + col];
                    float o  = g * al_reg[j] + (1.0f - g) * xv;
                    nt_store_f32(Out + (size_t)row * (TT * HH) + (size_t)t * HH + col, o);
                    sc_store_b16(state + (size_t)row * HH + col, bf16b(o));
                }
            }
        }
        gbar_arrive(gs, ng, rb + 4);
    }
}

extern "C" void kernel_launch(void* const* d_in, const int* in_sizes, int n_in,
                              void* d_out, int out_size, void* d_ws, size_t ws_size,
                              hipStream_t stream) {
    (void)in_sizes; (void)n_in; (void)out_size; (void)ws_size;
    const float* X   = (const float*)d_in[0];
    const float* aw1 = (const float*)d_in[1];
    const float* ab1 = (const float*)d_in[2];
    const float* aw2 = (const float*)d_in[3];
    const float* ab2 = (const float*)d_in[4];
    const float* gw1 = (const float*)d_in[5];
    const float* gb1 = (const float*)d_in[6];
    const float* gw2 = (const float*)d_in[7];
    const float* gb2 = (const float*)d_in[8];
    float* Out = (float*)d_out;

    char* ws = (char*)d_ws;
    unsigned short* p_a1 = (unsigned short*)(ws);                 // 4 MB
    unsigned short* p_g1 = (unsigned short*)(ws + (4u  << 20));   // 4 MB
    unsigned short* p_a2 = (unsigned short*)(ws + (8u  << 20));   // 2 MB
    unsigned short* p_g2 = (unsigned short*)(ws + (10u << 20));   // 2 MB
    char* ctrl = ws + (12u << 20);
    unsigned* slots = (unsigned*)ctrl;                            // 4 grp x 64 u32
    unsigned short* state = (unsigned short*)(ctrl + 4096);       // 256 KB
    unsigned short* h1    = state + (size_t)BB * HH;              // 256 KB
    unsigned short* albf  = h1    + (size_t)BB * HH;              // 256 KB
    unsigned short* h2    = albf  + (size_t)BB * HH;              // 256 KB
    unsigned short* xbf   = (unsigned short*)(ws + (16u << 20));  // 128 MB

    pack_w_kernel<<<(64 * 64 * 64 + 255) / 256, 256, 0, stream>>>(aw1, p_a1, 2048, 1024);
    pack_w_kernel<<<(64 * 64 * 64 + 255) / 256, 256, 0, stream>>>(gw1, p_g1, 2048, 1024);
    pack_w_kernel<<<(64 * 32 * 64 + 255) / 256, 256, 0, stream>>>(aw2, p_a2, 1024, 1024);
    pack_w_kernel<<<(64 * 32 * 64 + 255) / 256, 256, 0, stream>>>(gw2, p_g2, 1024, 1024);
    {
        int n8 = BB * TT * HH / 8;
        pack_x_kernel<<<(n8 + 255) / 256, 256, 0, stream>>>(X, xbf, n8);
    }
    // Zero barrier slots + recurrent state every call (graph-replay safe).
    hipMemsetAsync(ctrl, 0, 4096 + (size_t)BB * HH * sizeof(unsigned short), stream);

    persist_kernel<<<NWG, NTH, 0, stream>>>(X, xbf, p_a1, ab1, p_a2, ab2,
                                            p_g1, gb1, p_g2, gb2,
                                            Out, state, h1, albf, h2, slots);
}